// Round 8
// baseline (41.047 us; speedup 1.0000x reference)
//
#include <hip/hip_runtime.h>
#include <math.h>

// ---- DCT basis with the 0.25 global scale folded symmetrically (BB = 0.5*B1)
// so  F[i,j,u*8+v] = BB[i][u]*BB[j][v]  works for BOTH forward and inverse.
#define H1 0.49039264020161522f
#define H2 0.46193976625564338f
#define H3 0.41573480615127262f
#define H4 0.35355339059327376f
#define H5 0.27778511650980111f
#define H6 0.19134171618254489f
#define H7 0.09754516100806413f

__device__ __constant__ float cBB[64] = {
  H4,  H1,  H2,  H3,  H4,  H5,  H6,  H7,
  H4,  H3,  H6, -H7, -H4, -H1, -H2, -H5,
  H4,  H5, -H6, -H1, -H4,  H7,  H2,  H3,
  H4,  H7, -H2, -H5,  H4,  H3, -H6, -H1,
  H4, -H7, -H2,  H5,  H4, -H3, -H6,  H1,
  H4, -H5, -H6,  H1, -H4, -H7,  H2, -H3,
  H4, -H3,  H6,  H7, -H4,  H1, -H2,  H5,
  H4, -H1,  H2, -H3,  H4, -H5,  H6, -H7,
};

__device__ __constant__ float cQ[64] = {
  16.f/255.f, 11.f/255.f, 10.f/255.f, 16.f/255.f, 24.f/255.f, 40.f/255.f, 51.f/255.f, 61.f/255.f,
  12.f/255.f, 12.f/255.f, 14.f/255.f, 19.f/255.f, 26.f/255.f, 58.f/255.f, 60.f/255.f, 55.f/255.f,
  14.f/255.f, 13.f/255.f, 16.f/255.f, 24.f/255.f, 40.f/255.f, 57.f/255.f, 69.f/255.f, 56.f/255.f,
  14.f/255.f, 17.f/255.f, 22.f/255.f, 29.f/255.f, 51.f/255.f, 87.f/255.f, 80.f/255.f, 62.f/255.f,
  18.f/255.f, 22.f/255.f, 37.f/255.f, 56.f/255.f, 68.f/255.f, 109.f/255.f, 103.f/255.f, 77.f/255.f,
  24.f/255.f, 35.f/255.f, 55.f/255.f, 64.f/255.f, 81.f/255.f, 104.f/255.f, 113.f/255.f, 92.f/255.f,
  49.f/255.f, 64.f/255.f, 78.f/255.f, 87.f/255.f, 103.f/255.f, 121.f/255.f, 120.f/255.f, 101.f/255.f,
  72.f/255.f, 92.f/255.f, 95.f/255.f, 98.f/255.f, 112.f/255.f, 100.f/255.f, 103.f/255.f, 99.f/255.f,
};

__device__ __forceinline__ float clampf(float x, float lo, float hi) {
    return fminf(fmaxf(x, lo), hi);
}
__device__ __forceinline__ float sgnf(float x) {
    return (x > 0.f) ? 1.f : ((x < 0.f) ? -1.f : 0.f);
}
// Wave-private LDS phases need only compiler ordering: same-wave LDS ops
// execute in program order on the LDS pipe; forbid compiler reordering.
__device__ __forceinline__ void wave_fence() {
    asm volatile("" ::: "memory");
    __builtin_amdgcn_wave_barrier();
}
// Cross-lane on the VALU pipe (DPP), replacing ds_swizzle-based __shfl_xor.
// CTRL 0xB1 = quad_perm(1,0,3,2) = lane^1; 0x128 = row_ror:8 = lane^8 in a
// 16-lane row (rotation by 8 on a 16-ring == xor 8).
template<int CTRL>
__device__ __forceinline__ float dppf(float x) {
    int v = __builtin_amdgcn_update_dpp(__float_as_int(x), __float_as_int(x),
                                        CTRL, 0xF, 0xF, false);
    return __int_as_float(v);
}

// 2 waves per 16x16 tile (128-thread WG). Wave w owns luma block-row w
// (2 blocks, 2 px/lane at lane l=(i,j)) and one chroma plane (w=0:U, w=1:V).
// Luma transforms are wave-local (private LDS staging, no barriers).
// Cross-wave coupling = chroma plane only: 2 s_barriers per iteration.
__global__ __launch_bounds__(128, 4)
void smooth_jpeg_kernel(const float* __restrict__ s, float* __restrict__ out)
{
    const int t  = threadIdx.x;
    const int l  = t & 63;
    const int w  = t >> 6;
    const int li = l >> 3, lj = l & 7;

    const int tile = blockIdx.x;          // 4 * 32 * 32 tiles
    const int bb = tile >> 10;
    const int ti = tile & 1023;
    const int ty = (ti >> 5) * 16;
    const int tx = (ti & 31) * 16;

    __shared__ __align__(16) float BBr[64];        // BB row-major
    __shared__ __align__(16) float BBt[64];        // BBt[u][i] = BB[i][u]
    __shared__ __align__(16) float s1buf[2][256];  // per-wave staging A (inv: float2)
    __shared__ __align__(16) float s2buf[2][256];  // per-wave staging B (inv: float2)
    __shared__ __align__(16) float cuv[2][2][64];  // [parity][u/v][8x8] pooled
    __shared__ __align__(16) float cs1[2][128];    // chroma staging A (inv: float2)
    __shared__ __align__(16) float cs2[2][128];    // chroma staging B (inv: float2)
    __shared__ __align__(16) float cb[256];        // chroma px [u_r, v_r, u_w, v_w]

    if (t < 64) { BBr[t] = cBB[t]; BBt[t] = cBB[(t & 7)*8 + (t >> 3)]; }

    // pixel loads: blocks (w,0) and (w,1)
    const int gy = ty + w*8 + li;
    int pixo[2];
    float yrv[2], ygv[2], ybv[2];
    #pragma unroll
    for (int k = 0; k < 2; ++k) {
        pixo[k] = ((bb*512 + gy)*512 + (tx + k*8 + lj))*3;
        yrv[k] = s[pixo[k]+0];
        ygv[k] = s[pixo[k]+1];
        ybv[k] = s[pixo[k]+2];
    }

    // per-lane quant constants (lane's (u,v) = l for luma and chroma alike)
    const float q     = cQ[l];
    const float hqm   = 0.5f*q - (1.0f/510.0f);
    const float qhqm1 = q * hqm;
    const float qhqm3 = q * (1.0f + hqm);
    const float qhqp  = (0.5f*q + (1.0f/510.0f)) * q;

    const bool pooler = ((l & 9) == 0);            // i even && j even

    auto load8 = [](const float* p, float* d) {
        float4 a = *reinterpret_cast<const float4*>(p);
        float4 c = *reinterpret_cast<const float4*>(p + 4);
        d[0]=a.x; d[1]=a.y; d[2]=a.z; d[3]=a.w;
        d[4]=c.x; d[5]=c.y; d[6]=c.z; d[7]=c.w;
    };
    auto load8x2 = [](const float2* p, float2* d) {
        float4 a = *reinterpret_cast<const float4*>(p);
        float4 b = *reinterpret_cast<const float4*>(p + 2);
        float4 c = *reinterpret_cast<const float4*>(p + 4);
        float4 e = *reinterpret_cast<const float4*>(p + 6);
        d[0]=make_float2(a.x,a.y); d[1]=make_float2(a.z,a.w);
        d[2]=make_float2(b.x,b.y); d[3]=make_float2(b.z,b.w);
        d[4]=make_float2(c.x,c.y); d[5]=make_float2(c.z,c.w);
        d[6]=make_float2(e.x,e.y); d[7]=make_float2(e.z,e.w);
    };

    // color transform (2 px) + 2x2 chroma pool via DPP (VALU pipe) -> cuv[par]
    auto phaseA = [&](const float* pr, const float* pg, const float* pb,
                      float* pY, int par) {
        #pragma unroll
        for (int k = 0; k < 2; ++k) {
            float yv = 0.299f*pr[k] + 0.587f*pg[k] + 0.114f*pb[k] - 0.5f;
            float uu = -0.14714119f*pr[k] - 0.28886916f*pg[k] + 0.43601035f*pb[k];
            float vv =  0.61497538f*pr[k] - 0.51496512f*pg[k] - 0.10001026f*pb[k];
            pY[k] = yv;
            float ub = dppf<0xB1>(uu);          // lane^1
            float uc = dppf<0x128>(uu);         // lane^8
            float ud = dppf<0xB1>(uc);          // lane^9
            float vb = dppf<0xB1>(vv);
            float vc = dppf<0x128>(vv);
            float vd = dppf<0xB1>(vc);
            if (pooler) {
                int ci = (w*4 + (li>>1))*8 + k*4 + (lj>>1);
                cuv[par][0][ci] = 0.25f * (((uu + ub) + uc) + ud);
                cuv[par][1][ci] = 0.25f * (((vv + vb) + vc) + vd);
            }
        }
    };

    // basis rows/cols in registers (loaded once after the init barrier)
    float btR[8], buR[8], bjR[8], biR[8];

    // forward DCT: 2 luma blocks (wave-local) + this wave's chroma plane.
    // MUST be called after a real barrier (reads cuv written by both waves).
    auto fwdAll = [&](const float* pY, float* wy, float& wc, int par) {
        #pragma unroll
        for (int k = 0; k < 2; ++k) s1buf[w][k*64 + l] = pY[k];
        wave_fence();
        float rs[2], rsc;
        #pragma unroll
        for (int k = 0; k < 2; ++k) {
            float c8[8]; load8(&s1buf[w][k*64 + li*8], c8);
            float a = 0.f;
            #pragma unroll
            for (int j = 0; j < 8; ++j) a = fmaf(c8[j], btR[j], a);
            rs[k] = a;
        }
        {
            float c8[8]; load8(&cuv[par][w][li*8], c8);
            float a = 0.f;
            #pragma unroll
            for (int j = 0; j < 8; ++j) a = fmaf(c8[j], btR[j], a);
            rsc = a;
        }
        wave_fence();
        #pragma unroll
        for (int k = 0; k < 2; ++k) s2buf[w][k*64 + lj*8 + li] = rs[k];
        cs1[w][lj*8 + li] = rsc;
        wave_fence();
        #pragma unroll
        for (int k = 0; k < 2; ++k) {
            float c8[8]; load8(&s2buf[w][k*64 + lj*8], c8);
            float a = 0.f;
            #pragma unroll
            for (int i = 0; i < 8; ++i) a = fmaf(c8[i], buR[i], a);
            wy[k] = a;
        }
        {
            float c8[8]; load8(&cs1[w][lj*8], c8);
            float a = 0.f;
            #pragma unroll
            for (int i = 0; i < 8; ++i) a = fmaf(c8[i], buR[i], a);
            wc = a;
        }
    };

    // quantization adjustment (expressions identical to passing round-7 kernel)
    auto quant = [&](float wx, float neg, float& byS, float& uuS,
                     float& r_out, float& wz_out) {
        float axc = -0.8f*byS - 0.2f*neg;      // (1-a)By - (2-a)negC
        float r   = -axc - wx - uuS;
        float yq  = wx + 0.5f*r;
        float r0  = rintf(yq / q);
        float ry  = q * r0;
        float sgn = sgnf(r);
        float aa  = 0.5f*fabsf(r);
        float b1  = fabsf(ry - yq - sgn*qhqm1);
        float b3  = fabsf(ry - yq - sgn*qhqm3);
        float c1  = -sgn * fminf(aa, b1);
        float c3  = -sgn * fminf(aa, b3);
        float sarg = yq - ry - 0.5f*r;
        float sg2  = sgnf(sarg);
        float c2   = ry - qhqp*sg2 - yq;
        // c2's point sits hqp*q from ry, hqp < 0.25 q-units -> rint == r0 exactly.
        float rint1 = rintf((yq + c1) / q);
        float rint3 = rintf((yq + c3) / q);
        float rint2 = r0;
        float a1 = 0.5f*r + c1;
        float a2 = 0.5f*r + c2;
        float a3 = 0.5f*r + c3;
        float e1 = (-0.5f + q*rint1) - yq;
        float e2 = (-0.5f + q*rint2) - yq;
        float e3 = (-0.5f + q*rint3) - yq;
        float err1 = 0.5f*a1*a1 + 0.5f*e1*e1;
        float err2 = 0.5f*a2*a2 + 0.5f*e2*e2;
        float err3 = 0.5f*a3*a3 + 0.5f*e3*e3;
        bool p2 = err2 < err1;
        float best = p2 ? c2 : c1;
        float ebst = p2 ? err2 : err1;
        float rbst = p2 ? rint2 : rint1;
        bool p3 = err3 < ebst;
        float wdz  = p3 ? c3 : best;
        float rwin = p3 ? rint3 : rbst;        // == rint((yq+wdz)/q) bit-exactly
        r_out  = r;
        wz_out = wdz;
        byS = q * rwin;
        uuS = (uuS + axc) + byS;
    };

    // inverse DCT: r/wz packed as float2 (halves staging writes; identical
    // per-chain fmaf order). Writes chroma pixel planes into cb.
    auto invAll = [&](const float* rY, const float* wzY, float rC, float wzC,
                      float* accR, float* accW) {
        float2* p1 = reinterpret_cast<float2*>(s1buf[w]);
        float2* c1 = reinterpret_cast<float2*>(cs1[w]);
        #pragma unroll
        for (int k = 0; k < 2; ++k) p1[k*64 + l] = make_float2(rY[k], wzY[k]);
        c1[l] = make_float2(rC, wzC);
        wave_fence();
        float2 rr[2], rcc;
        #pragma unroll
        for (int k = 0; k < 2; ++k) {
            float2 c8[8]; load8x2(&p1[k*64 + li*8], c8);
            float ar = 0.f, aw = 0.f;
            #pragma unroll
            for (int v = 0; v < 8; ++v) {
                ar = fmaf(c8[v].x, bjR[v], ar);
                aw = fmaf(c8[v].y, bjR[v], aw);
            }
            rr[k] = make_float2(ar, aw);
        }
        {
            float2 c8[8]; load8x2(&c1[li*8], c8);
            float ar = 0.f, aw = 0.f;
            #pragma unroll
            for (int v = 0; v < 8; ++v) {
                ar = fmaf(c8[v].x, bjR[v], ar);
                aw = fmaf(c8[v].y, bjR[v], aw);
            }
            rcc = make_float2(ar, aw);
        }
        wave_fence();
        float2* p2  = reinterpret_cast<float2*>(s2buf[w]);
        float2* c2p = reinterpret_cast<float2*>(cs2[w]);
        #pragma unroll
        for (int k = 0; k < 2; ++k) p2[k*64 + lj*8 + li] = rr[k];
        c2p[lj*8 + li] = rcc;
        wave_fence();
        #pragma unroll
        for (int k = 0; k < 2; ++k) {
            float2 c8[8]; load8x2(&p2[k*64 + lj*8], c8);
            float ar = 0.f, aw = 0.f;
            #pragma unroll
            for (int u = 0; u < 8; ++u) {
                ar = fmaf(c8[u].x, biR[u], ar);
                aw = fmaf(c8[u].y, biR[u], aw);
            }
            accR[k] = ar;
            accW[k] = aw;
        }
        {
            float2 c8[8]; load8x2(&c2p[lj*8], c8);
            float ar = 0.f, aw = 0.f;
            #pragma unroll
            for (int u = 0; u < 8; ++u) {
                ar = fmaf(c8[u].x, biR[u], ar);
                aw = fmaf(c8[u].y, biR[u], aw);
            }
            cb[w*64 + l]       = ar;   // [0]=u_r, [64]=v_r
            cb[128 + w*64 + l] = aw;   // [128]=u_w, [192]=v_w
        }
    };

    // ---- init: Ws = W(s); negC = Q*round(Ws/Q); By = negC; u = 0; y = s ----
    float negY[2], byY[2], uY[2];
    float negC, byC, uC;
    {
        float pY[2], wy[2], wc;
        phaseA(yrv, ygv, ybv, pY, 0);
        __syncthreads();                   // B_init: BB tables + pooled plane
        load8(&BBt[lj*8], btR);            // BB[j][v=lj] over j
        load8(&BBt[li*8], buR);            // BB[i][u=li] over i
        load8(&BBr[lj*8], bjR);            // BB[j=lj][v] over v
        load8(&BBr[li*8], biR);            // BB[i=li][u] over u
        fwdAll(pY, wy, wc, 0);
        #pragma unroll
        for (int k = 0; k < 2; ++k) {
            negY[k] = q * rintf(wy[k] / q); byY[k] = negY[k]; uY[k] = 0.f;
        }
        negC = q * rintf(wc / q); byC = negC; uC = 0.f;
    }

    #pragma unroll 1
    for (int it = 0; it < 4; ++it) {
        const int par = (it + 1) & 1;      // parity double-buffer for cuv
        float xr[2], xg[2], xb[2], pY[2];
        #pragma unroll
        for (int k = 0; k < 2; ++k) {
            xr[k] = yrv[k] * (1.0f/3.0f);  // xup(y) == y/3 (A == 3 exactly)
            xg[k] = ygv[k] * (1.0f/3.0f);
            xb[k] = ybv[k] * (1.0f/3.0f);
        }
        phaseA(xr, xg, xb, pY, par);
        __syncthreads();                   // B1: pooled plane ready

        float wy[2], wc;
        fwdAll(pY, wy, wc, par);

        float rY[2], wzY[2], rC, wzC;
        #pragma unroll
        for (int k = 0; k < 2; ++k) quant(wy[k], negY[k], byY[k], uY[k], rY[k], wzY[k]);
        quant(wc, negC, byC, uC, rC, wzC);

        float accR[2], accW[2];
        invAll(rY, wzY, rC, wzC, accR, accW);
        __syncthreads();                   // B2: chroma pixel planes ready

        // ---- combine: y = x + 0.5*Wt(r) + Wt(wdz) ----
        #pragma unroll
        for (int k = 0; k < 2; ++k) {
            int kuv = (w*4 + (li>>1))*8 + k*4 + (lj>>1);
            float uR = clampf(cb[kuv],        -0.5f, 0.5f);
            float vR = clampf(cb[64 + kuv],   -0.5f, 0.5f);
            float uW = clampf(cb[128 + kuv],  -0.5f, 0.5f);
            float vW = clampf(cb[192 + kuv],  -0.5f, 0.5f);
            float yR = clampf(accR[k] + 0.5f, 0.f, 1.f);
            float yW = clampf(accW[k] + 0.5f, 0.f, 1.f);
            float rR = clampf(yR + 1.13988303f*vR, 0.f, 1.f);
            float gR = clampf(yR - 0.394642334f*uR - 0.58062185f*vR, 0.f, 1.f);
            float bR = clampf(yR + 2.03206185f*uR, 0.f, 1.f);
            float rW = clampf(yW + 1.13988303f*vW, 0.f, 1.f);
            float gW = clampf(yW - 0.394642334f*uW - 0.58062185f*vW, 0.f, 1.f);
            float bW = clampf(yW + 2.03206185f*uW, 0.f, 1.f);
            yrv[k] = xr[k] + 0.5f*rR + rW;
            ygv[k] = xg[k] + 0.5f*gR + gW;
            ybv[k] = xb[k] + 0.5f*bR + bW;
        }
    }

    // final xup(y) == y/3
    #pragma unroll
    for (int k = 0; k < 2; ++k) {
        out[pixo[k]+0] = yrv[k] * (1.0f/3.0f);
        out[pixo[k]+1] = ygv[k] * (1.0f/3.0f);
        out[pixo[k]+2] = ybv[k] * (1.0f/3.0f);
    }
}

extern "C" void kernel_launch(void* const* d_in, const int* in_sizes, int n_in,
                              void* d_out, int out_size, void* d_ws, size_t ws_size,
                              hipStream_t stream) {
    const float* s = (const float*)d_in[0];
    float* out = (float*)d_out;
    smooth_jpeg_kernel<<<dim3(4096), dim3(128), 0, stream>>>(s, out);
}

// Round 9
// 39.322 us; speedup vs baseline: 1.0439x; 1.0439x over previous
//
#include <hip/hip_runtime.h>
#include <math.h>

// ---- DCT basis with the 0.25 global scale folded symmetrically (BB = 0.5*B1)
// so  F[i,j,u*8+v] = BB[i][u]*BB[j][v]  works for BOTH forward and inverse.
#define H1 0.49039264020161522f
#define H2 0.46193976625564338f
#define H3 0.41573480615127262f
#define H4 0.35355339059327376f
#define H5 0.27778511650980111f
#define H6 0.19134171618254489f
#define H7 0.09754516100806413f

__device__ __constant__ float cBB[64] = {
  H4,  H1,  H2,  H3,  H4,  H5,  H6,  H7,
  H4,  H3,  H6, -H7, -H4, -H1, -H2, -H5,
  H4,  H5, -H6, -H1, -H4,  H7,  H2,  H3,
  H4,  H7, -H2, -H5,  H4,  H3, -H6, -H1,
  H4, -H7, -H2,  H5,  H4, -H3, -H6,  H1,
  H4, -H5, -H6,  H1, -H4, -H7,  H2, -H3,
  H4, -H3,  H6,  H7, -H4,  H1, -H2,  H5,
  H4, -H1,  H2, -H3,  H4, -H5,  H6, -H7,
};

__device__ __constant__ float cQ[64] = {
  16.f/255.f, 11.f/255.f, 10.f/255.f, 16.f/255.f, 24.f/255.f, 40.f/255.f, 51.f/255.f, 61.f/255.f,
  12.f/255.f, 12.f/255.f, 14.f/255.f, 19.f/255.f, 26.f/255.f, 58.f/255.f, 60.f/255.f, 55.f/255.f,
  14.f/255.f, 13.f/255.f, 16.f/255.f, 24.f/255.f, 40.f/255.f, 57.f/255.f, 69.f/255.f, 56.f/255.f,
  14.f/255.f, 17.f/255.f, 22.f/255.f, 29.f/255.f, 51.f/255.f, 87.f/255.f, 80.f/255.f, 62.f/255.f,
  18.f/255.f, 22.f/255.f, 37.f/255.f, 56.f/255.f, 68.f/255.f, 109.f/255.f, 103.f/255.f, 77.f/255.f,
  24.f/255.f, 35.f/255.f, 55.f/255.f, 64.f/255.f, 81.f/255.f, 104.f/255.f, 113.f/255.f, 92.f/255.f,
  49.f/255.f, 64.f/255.f, 78.f/255.f, 87.f/255.f, 103.f/255.f, 121.f/255.f, 120.f/255.f, 101.f/255.f,
  72.f/255.f, 92.f/255.f, 95.f/255.f, 98.f/255.f, 112.f/255.f, 100.f/255.f, 103.f/255.f, 99.f/255.f,
};

__device__ __forceinline__ float clampf(float x, float lo, float hi) {
    return fminf(fmaxf(x, lo), hi);
}
__device__ __forceinline__ float sgnf(float x) {
    return (x > 0.f) ? 1.f : ((x < 0.f) ? -1.f : 0.f);
}
// Wave-private LDS phases need only compiler ordering: same-wave LDS ops
// execute in program order on the LDS pipe; forbid compiler reordering.
__device__ __forceinline__ void wave_fence() {
    asm volatile("" ::: "memory");
    __builtin_amdgcn_wave_barrier();
}
// Cross-lane on the VALU pipe (DPP), replacing ds_swizzle-based __shfl_xor.
// CTRL 0xB1 = quad_perm(1,0,3,2) = lane^1; 0x128 = row_ror:8 = lane^8 in a
// 16-lane row (rotation by 8 on a 16-ring == xor 8). Verified passing in R8.
template<int CTRL>
__device__ __forceinline__ float dppf(float x) {
    int v = __builtin_amdgcn_update_dpp(__float_as_int(x), __float_as_int(x),
                                        CTRL, 0xF, 0xF, false);
    return __int_as_float(v);
}

// 2 waves per 16x16 tile (128-thread WG). Wave w owns luma block-row w
// (2 blocks, 2 px/lane at lane l=(i,j)) and one chroma plane (w=0:U, w=1:V).
// Luma transforms are wave-local (private LDS staging, no barriers).
// Cross-wave coupling = chroma plane only: 2 s_barriers per iteration.
// Basis rows/cols live in registers (hoisted once) -- saves ~8 ds_read_b128
// per lane per iteration on the per-CU LDS pipe, which is the bottleneck.
__global__ __launch_bounds__(128, 4)
void smooth_jpeg_kernel(const float* __restrict__ s, float* __restrict__ out)
{
    const int t  = threadIdx.x;
    const int l  = t & 63;
    const int w  = t >> 6;
    const int li = l >> 3, lj = l & 7;

    const int tile = blockIdx.x;          // 4 * 32 * 32 tiles
    const int bb = tile >> 10;
    const int ti = tile & 1023;
    const int ty = (ti >> 5) * 16;
    const int tx = (ti & 31) * 16;

    __shared__ __align__(16) float BBr[64];        // BB row-major
    __shared__ __align__(16) float BBt[64];        // BBt[u][i] = BB[i][u]
    __shared__ __align__(16) float lya[2][128];    // per-wave luma staging A
    __shared__ __align__(16) float lyb[2][128];    // per-wave luma staging B
    __shared__ __align__(16) float cuv[2][2][64];  // [parity][u/v][8x8] pooled
    __shared__ __align__(16) float cst[2][128];    // per-wave chroma staging
    __shared__ __align__(16) float cb[256];        // chroma px [u_r, v_r, u_w, v_w]

    if (t < 64) { BBr[t] = cBB[t]; BBt[t] = cBB[(t & 7)*8 + (t >> 3)]; }

    // pixel loads: blocks (w,0) and (w,1)
    const int gy = ty + w*8 + li;
    int pixo[2];
    float yrv[2], ygv[2], ybv[2];
    #pragma unroll
    for (int k = 0; k < 2; ++k) {
        pixo[k] = ((bb*512 + gy)*512 + (tx + k*8 + lj))*3;
        yrv[k] = s[pixo[k]+0];
        ygv[k] = s[pixo[k]+1];
        ybv[k] = s[pixo[k]+2];
    }

    // per-lane quant constants (lane's (u,v) = l for luma and chroma alike)
    const float q     = cQ[l];
    const float hqm   = 0.5f*q - (1.0f/510.0f);
    const float qhqm1 = q * hqm;
    const float qhqm3 = q * (1.0f + hqm);
    const float qhqp  = (0.5f*q + (1.0f/510.0f)) * q;

    const bool pooler = ((l & 9) == 0);            // i even && j even

    auto load8 = [](const float* p, float* d) {
        float4 a = *reinterpret_cast<const float4*>(p);
        float4 c = *reinterpret_cast<const float4*>(p + 4);
        d[0]=a.x; d[1]=a.y; d[2]=a.z; d[3]=a.w;
        d[4]=c.x; d[5]=c.y; d[6]=c.z; d[7]=c.w;
    };

    // color transform (2 px) + 2x2 chroma pool via DPP (VALU pipe) -> cuv[par]
    auto phaseA = [&](const float* pr, const float* pg, const float* pb,
                      float* pY, int par) {
        #pragma unroll
        for (int k = 0; k < 2; ++k) {
            float yv = 0.299f*pr[k] + 0.587f*pg[k] + 0.114f*pb[k] - 0.5f;
            float uu = -0.14714119f*pr[k] - 0.28886916f*pg[k] + 0.43601035f*pb[k];
            float vv =  0.61497538f*pr[k] - 0.51496512f*pg[k] - 0.10001026f*pb[k];
            pY[k] = yv;
            float ub = dppf<0xB1>(uu);          // lane^1
            float uc = dppf<0x128>(uu);         // lane^8
            float ud = dppf<0xB1>(uc);          // lane^9
            float vb = dppf<0xB1>(vv);
            float vc = dppf<0x128>(vv);
            float vd = dppf<0xB1>(vc);
            if (pooler) {
                int ci = (w*4 + (li>>1))*8 + k*4 + (lj>>1);
                cuv[par][0][ci] = 0.25f * (((uu + ub) + uc) + ud);
                cuv[par][1][ci] = 0.25f * (((vv + vb) + vc) + vd);
            }
        }
    };

    // basis rows/cols in registers (loaded once after the init barrier)
    float btR[8], buR[8], bjR[8], biR[8];

    // forward DCT: 2 luma blocks (wave-local) + this wave's chroma plane.
    // MUST be called after a real barrier (reads cuv written by both waves).
    auto fwdAll = [&](const float* pY, float* wy, float& wc, int par) {
        #pragma unroll
        for (int k = 0; k < 2; ++k) lya[w][k*64 + l] = pY[k];
        wave_fence();
        float rs[2], rsc;
        #pragma unroll
        for (int k = 0; k < 2; ++k) {
            float c8[8]; load8(&lya[w][k*64 + li*8], c8);
            float a = 0.f;
            #pragma unroll
            for (int j = 0; j < 8; ++j) a = fmaf(c8[j], btR[j], a);
            rs[k] = a;
        }
        {
            float c8[8]; load8(&cuv[par][w][li*8], c8);
            float a = 0.f;
            #pragma unroll
            for (int j = 0; j < 8; ++j) a = fmaf(c8[j], btR[j], a);
            rsc = a;
        }
        wave_fence();
        #pragma unroll
        for (int k = 0; k < 2; ++k) lyb[w][k*64 + lj*8 + li] = rs[k];
        cst[w][lj*8 + li] = rsc;
        wave_fence();
        #pragma unroll
        for (int k = 0; k < 2; ++k) {
            float c8[8]; load8(&lyb[w][k*64 + lj*8], c8);
            float a = 0.f;
            #pragma unroll
            for (int i = 0; i < 8; ++i) a = fmaf(c8[i], buR[i], a);
            wy[k] = a;
        }
        {
            float c8[8]; load8(&cst[w][lj*8], c8);
            float a = 0.f;
            #pragma unroll
            for (int i = 0; i < 8; ++i) a = fmaf(c8[i], buR[i], a);
            wc = a;
        }
    };

    // quantization adjustment (expressions identical to passing round-7 kernel)
    auto quant = [&](float wx, float neg, float& byS, float& uuS,
                     float& r_out, float& wz_out) {
        float axc = -0.8f*byS - 0.2f*neg;      // (1-a)By - (2-a)negC
        float r   = -axc - wx - uuS;
        float yq  = wx + 0.5f*r;
        float r0  = rintf(yq / q);
        float ry  = q * r0;
        float sgn = sgnf(r);
        float aa  = 0.5f*fabsf(r);
        float b1  = fabsf(ry - yq - sgn*qhqm1);
        float b3  = fabsf(ry - yq - sgn*qhqm3);
        float c1  = -sgn * fminf(aa, b1);
        float c3  = -sgn * fminf(aa, b3);
        float sarg = yq - ry - 0.5f*r;
        float sg2  = sgnf(sarg);
        float c2   = ry - qhqp*sg2 - yq;
        // c2's point sits hqp*q from ry, hqp < 0.25 q-units -> rint == r0 exactly.
        float rint1 = rintf((yq + c1) / q);
        float rint3 = rintf((yq + c3) / q);
        float rint2 = r0;
        float a1 = 0.5f*r + c1;
        float a2 = 0.5f*r + c2;
        float a3 = 0.5f*r + c3;
        float e1 = (-0.5f + q*rint1) - yq;
        float e2 = (-0.5f + q*rint2) - yq;
        float e3 = (-0.5f + q*rint3) - yq;
        float err1 = 0.5f*a1*a1 + 0.5f*e1*e1;
        float err2 = 0.5f*a2*a2 + 0.5f*e2*e2;
        float err3 = 0.5f*a3*a3 + 0.5f*e3*e3;
        bool p2 = err2 < err1;
        float best = p2 ? c2 : c1;
        float ebst = p2 ? err2 : err1;
        float rbst = p2 ? rint2 : rint1;
        bool p3 = err3 < ebst;
        float wdz  = p3 ? c3 : best;
        float rwin = p3 ? rint3 : rbst;        // == rint((yq+wdz)/q) bit-exactly
        r_out  = r;
        wz_out = wdz;
        byS = q * rwin;
        uuS = (uuS + axc) + byS;
    };

    // inverse DCT: 4 luma sets (r,wz x 2 blk, wave-local) + 2 chroma sets.
    // Writes chroma pixel planes into cb (consumed after the next barrier).
    auto invAll = [&](const float* rY, const float* wzY, float rC, float wzC,
                      float* accR, float* accW) {
        #pragma unroll
        for (int k = 0; k < 2; ++k) { lya[w][k*64 + l] = rY[k]; lyb[w][k*64 + l] = wzY[k]; }
        cst[w][l]      = rC;
        cst[w][64 + l] = wzC;
        wave_fence();
        float rr[2], rw[2], rcr, rcw;
        #pragma unroll
        for (int k = 0; k < 2; ++k) {
            float c8[8];
            load8(&lya[w][k*64 + li*8], c8);
            float a = 0.f;
            #pragma unroll
            for (int v = 0; v < 8; ++v) a = fmaf(c8[v], bjR[v], a);
            rr[k] = a;
            load8(&lyb[w][k*64 + li*8], c8);
            a = 0.f;
            #pragma unroll
            for (int v = 0; v < 8; ++v) a = fmaf(c8[v], bjR[v], a);
            rw[k] = a;
        }
        {
            float c8[8];
            load8(&cst[w][li*8], c8);
            float a = 0.f;
            #pragma unroll
            for (int v = 0; v < 8; ++v) a = fmaf(c8[v], bjR[v], a);
            rcr = a;
            load8(&cst[w][64 + li*8], c8);
            a = 0.f;
            #pragma unroll
            for (int v = 0; v < 8; ++v) a = fmaf(c8[v], bjR[v], a);
            rcw = a;
        }
        wave_fence();
        #pragma unroll
        for (int k = 0; k < 2; ++k) {
            lya[w][k*64 + lj*8 + li] = rr[k];
            lyb[w][k*64 + lj*8 + li] = rw[k];
        }
        cst[w][lj*8 + li]      = rcr;
        cst[w][64 + lj*8 + li] = rcw;
        wave_fence();
        #pragma unroll
        for (int k = 0; k < 2; ++k) {
            float c8[8];
            load8(&lya[w][k*64 + lj*8], c8);
            float a = 0.f;
            #pragma unroll
            for (int u = 0; u < 8; ++u) a = fmaf(c8[u], biR[u], a);
            accR[k] = a;
            load8(&lyb[w][k*64 + lj*8], c8);
            a = 0.f;
            #pragma unroll
            for (int u = 0; u < 8; ++u) a = fmaf(c8[u], biR[u], a);
            accW[k] = a;
        }
        float pcr, pcw;
        {
            float c8[8];
            load8(&cst[w][lj*8], c8);
            float a = 0.f;
            #pragma unroll
            for (int u = 0; u < 8; ++u) a = fmaf(c8[u], biR[u], a);
            pcr = a;
            load8(&cst[w][64 + lj*8], c8);
            a = 0.f;
            #pragma unroll
            for (int u = 0; u < 8; ++u) a = fmaf(c8[u], biR[u], a);
            pcw = a;
        }
        cb[w*64 + l]       = pcr;   // [0]=u_r, [64]=v_r
        cb[128 + w*64 + l] = pcw;   // [128]=u_w, [192]=v_w
    };

    // ---- init: Ws = W(s); negC = Q*round(Ws/Q); By = negC; u = 0; y = s ----
    float negY[2], byY[2], uY[2];
    float negC, byC, uC;
    {
        float pY[2], wy[2], wc;
        phaseA(yrv, ygv, ybv, pY, 0);
        __syncthreads();                   // B_init: BB tables + pooled plane
        load8(&BBt[lj*8], btR);            // BB[j][v=lj] over j
        load8(&BBt[li*8], buR);            // BB[i][u=li] over i
        load8(&BBr[lj*8], bjR);            // BB[j=lj][v] over v
        load8(&BBr[li*8], biR);            // BB[i=li][u] over u
        fwdAll(pY, wy, wc, 0);
        #pragma unroll
        for (int k = 0; k < 2; ++k) {
            negY[k] = q * rintf(wy[k] / q); byY[k] = negY[k]; uY[k] = 0.f;
        }
        negC = q * rintf(wc / q); byC = negC; uC = 0.f;
    }

    #pragma unroll 1
    for (int it = 0; it < 4; ++it) {
        const int par = (it + 1) & 1;      // parity double-buffer for cuv
        float xr[2], xg[2], xb[2], pY[2];
        #pragma unroll
        for (int k = 0; k < 2; ++k) {
            xr[k] = yrv[k] * (1.0f/3.0f);  // xup(y) == y/3 (A == 3 exactly)
            xg[k] = ygv[k] * (1.0f/3.0f);
            xb[k] = ybv[k] * (1.0f/3.0f);
        }
        phaseA(xr, xg, xb, pY, par);
        __syncthreads();                   // B1: pooled plane ready

        float wy[2], wc;
        fwdAll(pY, wy, wc, par);

        float rY[2], wzY[2], rC, wzC;
        #pragma unroll
        for (int k = 0; k < 2; ++k) quant(wy[k], negY[k], byY[k], uY[k], rY[k], wzY[k]);
        quant(wc, negC, byC, uC, rC, wzC);

        float accR[2], accW[2];
        invAll(rY, wzY, rC, wzC, accR, accW);
        __syncthreads();                   // B2: chroma pixel planes ready

        // ---- combine: y = x + 0.5*Wt(r) + Wt(wdz) ----
        #pragma unroll
        for (int k = 0; k < 2; ++k) {
            int kuv = (w*4 + (li>>1))*8 + k*4 + (lj>>1);
            float uR = clampf(cb[kuv],        -0.5f, 0.5f);
            float vR = clampf(cb[64 + kuv],   -0.5f, 0.5f);
            float uW = clampf(cb[128 + kuv],  -0.5f, 0.5f);
            float vW = clampf(cb[192 + kuv],  -0.5f, 0.5f);
            float yR = clampf(accR[k] + 0.5f, 0.f, 1.f);
            float yW = clampf(accW[k] + 0.5f, 0.f, 1.f);
            float rR = clampf(yR + 1.13988303f*vR, 0.f, 1.f);
            float gR = clampf(yR - 0.394642334f*uR - 0.58062185f*vR, 0.f, 1.f);
            float bR = clampf(yR + 2.03206185f*uR, 0.f, 1.f);
            float rW = clampf(yW + 1.13988303f*vW, 0.f, 1.f);
            float gW = clampf(yW - 0.394642334f*uW - 0.58062185f*vW, 0.f, 1.f);
            float bW = clampf(yW + 2.03206185f*uW, 0.f, 1.f);
            yrv[k] = xr[k] + 0.5f*rR + rW;
            ygv[k] = xg[k] + 0.5f*gR + gW;
            ybv[k] = xb[k] + 0.5f*bR + bW;
        }
    }

    // final xup(y) == y/3
    #pragma unroll
    for (int k = 0; k < 2; ++k) {
        out[pixo[k]+0] = yrv[k] * (1.0f/3.0f);
        out[pixo[k]+1] = ygv[k] * (1.0f/3.0f);
        out[pixo[k]+2] = ybv[k] * (1.0f/3.0f);
    }
}

extern "C" void kernel_launch(void* const* d_in, const int* in_sizes, int n_in,
                              void* d_out, int out_size, void* d_ws, size_t ws_size,
                              hipStream_t stream) {
    const float* s = (const float*)d_in[0];
    float* out = (float*)d_out;
    smooth_jpeg_kernel<<<dim3(4096), dim3(128), 0, stream>>>(s, out);
}